// Round 12
// baseline (77.395 us; speedup 1.0000x reference)
//
#include <hip/hip_runtime.h>

// GBDT ensemble inference — R12: scalar first macro-stage (root + PT0 via
// s_load + cndmask select) -> 3 VMEM gathers per walk (was 4).
// B=32768, T=512, D=8, F=512, C=1.
//
// ws layout (int4 records, 1.36 MB hot):
//   PT0 [0,1024):      levels 0,1   idx in [0,2T)    (scalar-loaded only)
//   PT1 [1024,5120):   levels 2,3   idx in [0,8T)
//   PT2 [5120,21504):  levels 4,5   idx in [0,32T)
//   PT3 [21504,87040): level 6+leaf idx in [0,128T)
// Pair rec: {f0|fL<<10|fR<<20, b0, bL, bR}; PT3 rec: {f6, b6, leafL, leafR}.
//
// Mapping: lane = batch row (64 rows/block), wave owns 32 trees; per step
// 8 chains (8 consecutive trees, wave-uniform -> all root/PT0 records scalar);
// leaves -> 2x float4 store.

#define BB 32768
#define TT 512
#define FF 512
#define PADW 65536
#define ROWS 64
#define THREADS 1024
#define TPW 32
#define XSS 515           // odd stride: correlated-feature lanes spread banks

#define PT0_OFF 0
#define PT1_OFF 1024
#define PT2_OFF 5120
#define PT3_OFF 21504
#define N_REC   87040

__global__ __launch_bounds__(256) void build_tables_kernel(
    const int*   __restrict__ nodes_lv,
    const float* __restrict__ biases_lv,
    const float* __restrict__ leaf_nodes,
    int4*        __restrict__ ws16)
{
    const int i = blockIdx.x * 256 + threadIdx.x;
    if (i >= N_REC) return;

    int l, p, off;
    if (i < PT1_OFF)      { l = 0; off = PT0_OFF; }
    else if (i < PT2_OFF) { l = 2; off = PT1_OFF; }
    else if (i < PT3_OFF) { l = 4; off = PT2_OFF; }
    else {
        p = i - PT3_OFF;
        const int   f  = nodes_lv[6 * PADW + p];
        const float b  = biases_lv[6 * PADW + p];
        const float lL = leaf_nodes[2 * p];
        const float lR = leaf_nodes[2 * p + 1];
        ws16[i] = make_int4(f, __float_as_int(b),
                            __float_as_int(lL), __float_as_int(lR));
        return;
    }
    p = i - off;
    const int   f0 = nodes_lv[l * PADW + p];
    const float b0 = biases_lv[l * PADW + p];
    const int   fL = nodes_lv[(l + 1) * PADW + 2 * p];
    const int   fR = nodes_lv[(l + 1) * PADW + 2 * p + 1];
    const float bL = biases_lv[(l + 1) * PADW + 2 * p];
    const float bR = biases_lv[(l + 1) * PADW + 2 * p + 1];
    ws16[i] = make_int4(f0 | (fL << 10) | (fR << 20), __float_as_int(b0),
                        __float_as_int(bL), __float_as_int(bR));
}

__global__ __launch_bounds__(THREADS) void gbdt_walk_kernel(
    const float* __restrict__ x,
    const int*   __restrict__ root_nodes,
    const float* __restrict__ root_biases,
    const int4*  __restrict__ ws16,
    float*       __restrict__ out)
{
    __shared__ float xs[ROWS * XSS];        // 131,840 B

    const int tid = threadIdx.x;
    const int b0  = blockIdx.x * ROWS;

    // ---- stage 64 x-rows into LDS ----
    const float4* __restrict__ xr = (const float4*)(x + (size_t)b0 * FF);
    #pragma unroll
    for (int i = 0; i < (ROWS * FF / 4) / THREADS; ++i) {   // 8 iters
        int fidx = i * THREADS + tid;
        int r = fidx >> 7, c4 = fidx & 127;
        float4 v = xr[fidx];
        float* d = &xs[r * XSS + (c4 << 2)];
        d[0] = v.x; d[1] = v.y; d[2] = v.z; d[3] = v.w;
    }
    __syncthreads();

    const int wv   = tid >> 6;
    const int lane = tid & 63;
    const int tb   = wv * TPW;
    const float* __restrict__ xrow = &xs[lane * XSS];
    float* __restrict__ orow = out + (size_t)(b0 + lane) * TT;

    #pragma unroll
    for (int s = 0; s < TPW / 8; ++s) {     // 4 steps, 8 chains each
        const int t0 = __builtin_amdgcn_readfirstlane(tb + 8 * s);
        int p[8];

        // ---- scalar macro-stage: root + PT0 (levels 0,1), no VMEM gather ----
        #pragma unroll
        for (int c = 0; c < 8; ++c) {
            const int t = t0 + c;           // wave-uniform
            // root: scalar-loaded feature id + threshold
            const bool rb = xrow[root_nodes[t]] >= root_biases[t];
            // both PT0 records are wave-uniform scalar loads
            const int4 rA = ws16[PT0_OFF + 2 * t];
            const int4 rB = ws16[PT0_OFF + 2 * t + 1];
            const int   fpA = rA.x, fpB = rB.x;
            const int   fp  = rb ? fpB : fpA;
            const float th0 = rb ? __int_as_float(rB.y) : __int_as_float(rA.y);
            const bool g0 = xrow[fp & 1023] >= th0;
            const int   f1 = g0 ? ((fp >> 20) & 1023) : ((fp >> 10) & 1023);
            const float h1 = g0 ? (rb ? __int_as_float(rB.w) : __int_as_float(rA.w))
                                : (rb ? __int_as_float(rB.z) : __int_as_float(rA.z));
            const bool g1 = xrow[f1] >= h1;
            p[c] = 8 * t + 4 * (int)rb + 2 * (int)g0 + (int)g1;   // in [8t, 8t+8)
        }

        // ---- two fused 2-level VMEM stages: PT1 (lvl 2,3), PT2 (lvl 4,5) ----
        const int offs[2] = { PT1_OFF, PT2_OFF };
        #pragma unroll
        for (int j = 0; j < 2; ++j) {
            int4 r[8];
            #pragma unroll
            for (int c = 0; c < 8; ++c) r[c] = ws16[offs[j] + p[c]];
            #pragma unroll
            for (int c = 0; c < 8; ++c) {
                const int   fp = r[c].x;
                const bool  g0 = xrow[fp & 1023] >= __int_as_float(r[c].y);
                const int   f1 = g0 ? ((fp >> 20) & 1023) : ((fp >> 10) & 1023);
                const float h1 = g0 ? __int_as_float(r[c].w) : __int_as_float(r[c].z);
                const bool  g1 = xrow[f1] >= h1;
                p[c] = 4 * p[c] + 2 * (int)g0 + (int)g1;
            }
        }

        // ---- final stage: level 6 + leaf in one record ----
        int4 r3[8];
        #pragma unroll
        for (int c = 0; c < 8; ++c) r3[c] = ws16[PT3_OFF + p[c]];
        float v[8];
        #pragma unroll
        for (int c = 0; c < 8; ++c) {
            const bool g = xrow[r3[c].x] >= __int_as_float(r3[c].y);
            v[c] = g ? __int_as_float(r3[c].w) : __int_as_float(r3[c].z);
        }
        *(float4*)&orow[t0]     = make_float4(v[0], v[1], v[2], v[3]);
        *(float4*)&orow[t0 + 4] = make_float4(v[4], v[5], v[6], v[7]);
    }
}

// Fallback (ws too small): direct gathers from the original tables.
__global__ __launch_bounds__(THREADS) void gbdt_walk_fallback(
    const float* __restrict__ x,
    const int*   __restrict__ root_nodes,
    const float* __restrict__ root_biases,
    const int*   __restrict__ nodes_lv,
    const float* __restrict__ biases_lv,
    const float* __restrict__ leaf_nodes,
    float*       __restrict__ out)
{
    __shared__ float xs[ROWS * XSS];
    const int tid = threadIdx.x;
    const int b0  = blockIdx.x * ROWS;
    const float4* __restrict__ xr = (const float4*)(x + (size_t)b0 * FF);
    #pragma unroll
    for (int i = 0; i < (ROWS * FF / 4) / THREADS; ++i) {
        int fidx = i * THREADS + tid;
        int r = fidx >> 7, c4 = fidx & 127;
        float4 v = xr[fidx];
        float* d = &xs[r * XSS + (c4 << 2)];
        d[0] = v.x; d[1] = v.y; d[2] = v.z; d[3] = v.w;
    }
    __syncthreads();
    const int wv   = tid >> 6;
    const int lane = tid & 63;
    const int tb   = wv * TPW;
    const float* __restrict__ xrow = &xs[lane * XSS];
    float* __restrict__ orow = out + (size_t)(b0 + lane) * TT;
    #pragma unroll
    for (int s = 0; s < TPW; ++s) {
        const int t = tb + s;
        int p = 2 * t + (xrow[root_nodes[t]] >= root_biases[t] ? 1 : 0);
        #pragma unroll
        for (int l = 0; l < 7; ++l) {
            const int   f = nodes_lv[l * PADW + p];
            const float h = biases_lv[l * PADW + p];
            p = 2 * p + (xrow[f] >= h ? 1 : 0);
        }
        orow[t] = leaf_nodes[p];
    }
}

extern "C" void kernel_launch(void* const* d_in, const int* in_sizes, int n_in,
                              void* d_out, int out_size, void* d_ws, size_t ws_size,
                              hipStream_t stream) {
    const float* x            = (const float*)d_in[0];
    const int*   root_nodes   = (const int*)  d_in[1];
    const float* root_biases  = (const float*)d_in[2];
    const int*   nodes_lv     = (const int*)  d_in[4];
    const float* biases_lv    = (const float*)d_in[5];
    const float* leaf_nodes   = (const float*)d_in[6];
    float*       out          = (float*)d_out;

    dim3 grid(BB / ROWS);   // 512 blocks
    dim3 block(THREADS);

    if (ws_size >= (size_t)N_REC * 16) {
        int4* ws16 = (int4*)d_ws;
        build_tables_kernel<<<(N_REC + 255) / 256, 256, 0, stream>>>(
            nodes_lv, biases_lv, leaf_nodes, ws16);
        gbdt_walk_kernel<<<grid, block, 0, stream>>>(
            x, root_nodes, root_biases, ws16, out);
    } else {
        gbdt_walk_fallback<<<grid, block, 0, stream>>>(
            x, root_nodes, root_biases, nodes_lv, biases_lv, leaf_nodes, out);
    }
}

// Round 13
// 68.547 us; speedup vs baseline: 1.1291x; 1.1291x over previous
//
#include <hip/hip_runtime.h>

// GBDT ensemble inference — R13: levels 0-3 fully LDS-resident.
// root(4KB) + PT0(16KB) + PT1(64KB) staged in LDS next to xs (32 rows, 66KB)
// -> VMEM gathers per walk: 4 -> 2 (PT2, PT3 only). 152 KB LDS, 1 block/CU.
// B=32768, T=512, D=8, F=512, C=1.
//
// ws16 layout (int4 records, built once per launch):
//   PT0 [0,1024):      levels 0,1   idx in [0,2T)    (staged to LDS)
//   PT1 [1024,5120):   levels 2,3   idx in [0,8T)    (staged to LDS)
//   PT2 [5120,21504):  levels 4,5   idx in [0,32T)   (VMEM)
//   PT3 [21504,87040): level 6+leaf idx in [0,128T)  (VMEM)
// Pair rec: {f0|fL<<10|fR<<20, b0, bL, bR}; PT3 rec: {f6, b6, leafL, leafR}.
//
// Mapping: lane = row (0..31) + tree-group g (lane>>5); wave owns 32 trees;
// per step 8 trees, lane handles 4 consecutive (tbase+c); float4 leaf stores.

#define BB 32768
#define TT 512
#define FF 512
#define PADW 65536
#define ROWS 32
#define THREADS 1024
#define TPW 32
#define XSS 515           // odd stride: correlated-feature lanes spread banks

#define PT0_OFF 0
#define PT1_OFF 1024
#define PT2_OFF 5120
#define PT3_OFF 21504
#define N_REC   87040

__global__ __launch_bounds__(256) void build_tables_kernel(
    const int*   __restrict__ nodes_lv,
    const float* __restrict__ biases_lv,
    const float* __restrict__ leaf_nodes,
    int4*        __restrict__ ws16)
{
    const int i = blockIdx.x * 256 + threadIdx.x;
    if (i >= N_REC) return;

    int l, p, off;
    if (i < PT1_OFF)      { l = 0; off = PT0_OFF; }
    else if (i < PT2_OFF) { l = 2; off = PT1_OFF; }
    else if (i < PT3_OFF) { l = 4; off = PT2_OFF; }
    else {
        p = i - PT3_OFF;
        const int   f  = nodes_lv[6 * PADW + p];
        const float b  = biases_lv[6 * PADW + p];
        const float lL = leaf_nodes[2 * p];
        const float lR = leaf_nodes[2 * p + 1];
        ws16[i] = make_int4(f, __float_as_int(b),
                            __float_as_int(lL), __float_as_int(lR));
        return;
    }
    p = i - off;
    const int   f0 = nodes_lv[l * PADW + p];
    const float b0 = biases_lv[l * PADW + p];
    const int   fL = nodes_lv[(l + 1) * PADW + 2 * p];
    const int   fR = nodes_lv[(l + 1) * PADW + 2 * p + 1];
    const float bL = biases_lv[(l + 1) * PADW + 2 * p];
    const float bR = biases_lv[(l + 1) * PADW + 2 * p + 1];
    ws16[i] = make_int4(f0 | (fL << 10) | (fR << 20), __float_as_int(b0),
                        __float_as_int(bL), __float_as_int(bR));
}

__global__ __launch_bounds__(THREADS) void gbdt_walk_kernel(
    const float* __restrict__ x,
    const int*   __restrict__ root_nodes,
    const float* __restrict__ root_biases,
    const int4*  __restrict__ ws16,
    float*       __restrict__ out)
{
    __shared__ float xs[ROWS * XSS];   // 65,920 B
    __shared__ int4  pt0[1024];        // 16,384 B (levels 0,1)
    __shared__ int4  pt1[4096];        // 65,536 B (levels 2,3)
    __shared__ int2  rt[512];          //  4,096 B (root f,b)   total 151,936 B

    const int tid = threadIdx.x;
    const int b0  = blockIdx.x * ROWS;

    // ---- stage x rows (coalesced float4) ----
    const float4* __restrict__ xr = (const float4*)(x + (size_t)b0 * FF);
    #pragma unroll
    for (int i = 0; i < (ROWS * FF / 4) / THREADS; ++i) {   // 4 iters
        int fidx = i * THREADS + tid;
        int r = fidx >> 7, c4 = fidx & 127;
        float4 v = xr[fidx];
        float* d = &xs[r * XSS + (c4 << 2)];
        d[0] = v.x; d[1] = v.y; d[2] = v.z; d[3] = v.w;
    }
    // ---- stage PT0+PT1 (5120 int4, coalesced) ----
    #pragma unroll
    for (int i = 0; i < 5; ++i) {
        int idx = i * THREADS + tid;
        if (idx < 5120) {
            int4 v = ws16[idx];                 // [PT0_OFF, PT2_OFF)
            if (idx < 1024) pt0[idx] = v;
            else            pt1[idx - 1024] = v;
        }
    }
    // ---- stage roots ----
    if (tid < 512)
        rt[tid] = make_int2(root_nodes[tid], __float_as_int(root_biases[tid]));
    __syncthreads();

    const int wv   = tid >> 6;              // wave 0..15
    const int lane = tid & 63;
    const int row  = lane & 31;
    const int g    = lane >> 5;             // tree-half within the step
    const int tb   = wv * TPW;
    const float* __restrict__ xrow = &xs[row * XSS];
    float* __restrict__ orow = out + (size_t)(b0 + row) * TT;

    #pragma unroll
    for (int s = 0; s < TPW / 8; ++s) {     // 4 steps, 8 trees each
        const int tbase = tb + 8 * s + 4 * g;   // lane owns 4 consecutive trees
        int p[4];

        // ---- LDS macro-stage A: root + PT0 (levels 0,1) ----
        #pragma unroll
        for (int c = 0; c < 4; ++c) {
            const int t = tbase + c;
            const int2 rn = rt[t];          // broadcast (2 addrs/wave)
            const bool rb = xrow[rn.x] >= __int_as_float(rn.y);
            p[c] = 2 * t + (int)rb;
        }
        {
            int4 r0[4];
            #pragma unroll
            for (int c = 0; c < 4; ++c) r0[c] = pt0[p[c]];
            #pragma unroll
            for (int c = 0; c < 4; ++c) {
                const int   fp = r0[c].x;
                const bool  g0 = xrow[fp & 1023] >= __int_as_float(r0[c].y);
                const int   f1 = g0 ? ((fp >> 20) & 1023) : ((fp >> 10) & 1023);
                const float h1 = g0 ? __int_as_float(r0[c].w) : __int_as_float(r0[c].z);
                const bool  g1 = xrow[f1] >= h1;
                p[c] = 4 * p[c] + 2 * (int)g0 + (int)g1;    // [8t, 8t+8)
            }
        }
        // ---- LDS macro-stage B: PT1 (levels 2,3) ----
        {
            int4 r1[4];
            #pragma unroll
            for (int c = 0; c < 4; ++c) r1[c] = pt1[p[c]];
            #pragma unroll
            for (int c = 0; c < 4; ++c) {
                const int   fp = r1[c].x;
                const bool  g0 = xrow[fp & 1023] >= __int_as_float(r1[c].y);
                const int   f1 = g0 ? ((fp >> 20) & 1023) : ((fp >> 10) & 1023);
                const float h1 = g0 ? __int_as_float(r1[c].w) : __int_as_float(r1[c].z);
                const bool  g1 = xrow[f1] >= h1;
                p[c] = 4 * p[c] + 2 * (int)g0 + (int)g1;    // [32t, 32t+32)
            }
        }
        // ---- VMEM stage: PT2 (levels 4,5) ----
        {
            int4 r2[4];
            #pragma unroll
            for (int c = 0; c < 4; ++c) r2[c] = ws16[PT2_OFF + p[c]];
            #pragma unroll
            for (int c = 0; c < 4; ++c) {
                const int   fp = r2[c].x;
                const bool  g0 = xrow[fp & 1023] >= __int_as_float(r2[c].y);
                const int   f1 = g0 ? ((fp >> 20) & 1023) : ((fp >> 10) & 1023);
                const float h1 = g0 ? __int_as_float(r2[c].w) : __int_as_float(r2[c].z);
                const bool  g1 = xrow[f1] >= h1;
                p[c] = 4 * p[c] + 2 * (int)g0 + (int)g1;    // [128t, 128t+128)
            }
        }
        // ---- VMEM stage: PT3 (level 6 + leaf) ----
        int4 r3[4];
        #pragma unroll
        for (int c = 0; c < 4; ++c) r3[c] = ws16[PT3_OFF + p[c]];
        float v[4];
        #pragma unroll
        for (int c = 0; c < 4; ++c) {
            const bool gg = xrow[r3[c].x] >= __int_as_float(r3[c].y);
            v[c] = gg ? __int_as_float(r3[c].w) : __int_as_float(r3[c].z);
        }
        *(float4*)&orow[tbase] = make_float4(v[0], v[1], v[2], v[3]);
    }
}

// Fallback (ws too small): direct gathers from the original tables.
__global__ __launch_bounds__(THREADS) void gbdt_walk_fallback(
    const float* __restrict__ x,
    const int*   __restrict__ root_nodes,
    const float* __restrict__ root_biases,
    const int*   __restrict__ nodes_lv,
    const float* __restrict__ biases_lv,
    const float* __restrict__ leaf_nodes,
    float*       __restrict__ out)
{
    __shared__ float xs[ROWS * XSS];
    const int tid = threadIdx.x;
    const int b0  = blockIdx.x * ROWS;
    const float4* __restrict__ xr = (const float4*)(x + (size_t)b0 * FF);
    #pragma unroll
    for (int i = 0; i < (ROWS * FF / 4) / THREADS; ++i) {
        int fidx = i * THREADS + tid;
        int r = fidx >> 7, c4 = fidx & 127;
        float4 v = xr[fidx];
        float* d = &xs[r * XSS + (c4 << 2)];
        d[0] = v.x; d[1] = v.y; d[2] = v.z; d[3] = v.w;
    }
    __syncthreads();
    const int wv   = tid >> 6;
    const int lane = tid & 63;
    const int row  = lane & 31;
    const int g    = lane >> 5;
    const int tb   = wv * TPW;
    const float* __restrict__ xrow = &xs[row * XSS];
    float* __restrict__ orow = out + (size_t)(b0 + row) * TT;
    #pragma unroll
    for (int s = 0; s < TPW / 2; ++s) {
        const int t = tb + 2 * s + g;
        int p = 2 * t + (xrow[root_nodes[t]] >= root_biases[t] ? 1 : 0);
        #pragma unroll
        for (int l = 0; l < 7; ++l) {
            const int   f = nodes_lv[l * PADW + p];
            const float h = biases_lv[l * PADW + p];
            p = 2 * p + (xrow[f] >= h ? 1 : 0);
        }
        orow[t] = leaf_nodes[p];
    }
}

extern "C" void kernel_launch(void* const* d_in, const int* in_sizes, int n_in,
                              void* d_out, int out_size, void* d_ws, size_t ws_size,
                              hipStream_t stream) {
    const float* x            = (const float*)d_in[0];
    const int*   root_nodes   = (const int*)  d_in[1];
    const float* root_biases  = (const float*)d_in[2];
    const int*   nodes_lv     = (const int*)  d_in[4];
    const float* biases_lv    = (const float*)d_in[5];
    const float* leaf_nodes   = (const float*)d_in[6];
    float*       out          = (float*)d_out;

    dim3 grid(BB / ROWS);   // 1024 blocks
    dim3 block(THREADS);

    if (ws_size >= (size_t)N_REC * 16) {
        int4* ws16 = (int4*)d_ws;
        build_tables_kernel<<<(N_REC + 255) / 256, 256, 0, stream>>>(
            nodes_lv, biases_lv, leaf_nodes, ws16);
        gbdt_walk_kernel<<<grid, block, 0, stream>>>(
            x, root_nodes, root_biases, ws16, out);
    } else {
        gbdt_walk_fallback<<<grid, block, 0, stream>>>(
            x, root_nodes, root_biases, nodes_lv, biases_lv, leaf_nodes, out);
    }
}